// Round 6
// baseline (186.699 us; speedup 1.0000x reference)
//
#include <hip/hip_runtime.h>

// Fully fused pipeline (h, f, pf never touch HBM):
//   k_fused: block (b, s=0..6) covers f-rows 4s..4s+3:
//     P1 conv1+relu+pool -> LDS h-tile[8][10][60] (rows gr=8s-1..8s+8, zero halo)
//     P2 conv2+relu+pool (thread = f-pixel x oc-half, oh wave-uniform)
//     P3 patch-linear -> pfl[112] (this tile's contiguous pf slice)
//     P4 fc1 partial: h1p[b][s][64] = w_fc1[:,112s..112s+111] . pfl
//   k_tail: h1 = relu(sum_s h1p + b_fc1); fc2; log_softmax -> out[512,10]
// All fp32.

#define HSTR 60  // 58 used cols (56 + 2 halo) + 2 pad (even stride -> aligned float2)

#define C9(J, K)                                                             \
  (win[J][K] * w0_ + win[J][K + 1] * w1_ + win[J][K + 2] * w2_ +             \
   win[J + 1][K] * w3_ + win[J + 1][K + 1] * w4_ + win[J + 1][K + 2] * w5_ + \
   win[J + 2][K] * w6_ + win[J + 2][K + 1] * w7_ + win[J + 2][K + 2] * w8_)

__global__ __launch_bounds__(256) void k_fused(
    const float* __restrict__ x, const float* __restrict__ w1,
    const float* __restrict__ b1, const float* __restrict__ w2,
    const float* __restrict__ b2, const float* __restrict__ wp,
    const float* __restrict__ bp, const float* __restrict__ w_fc1,
    float* __restrict__ h1p) {
  __shared__ __align__(16) float hs[8 * 10 * HSTR];  // 4800 floats, 19.2 KB
  __shared__ __align__(16) float pfh[28 * 32];       // [p_l][slot(8)][ot(4)]
  __shared__ __align__(16) float pfl[112];           // tile's pf slice
  const int tid = threadIdx.x;
  const int b = blockIdx.x / 7;
  const int s = blockIdx.x - 7 * b;

  for (int i = tid; i < 8 * 10 * HSTR; i += 256) hs[i] = 0.f;
  __syncthreads();

  // ---- Phase 1: conv1(1->8)+bias+relu+maxpool2 into LDS tile ----
  // tile row r 0..9 <-> global pooled-h row gr = 8s-1+r; halo rows/cols stay 0.
  const float* xb = x + (long)b * 12544;  // x[b], 112x112
  for (int task = tid; task < 560; task += 256) {
    int r = task / 56, hc = task % 56;
    int gr = 8 * s - 1 + r;
    if ((unsigned)gr >= 56u) continue;
    float win[4][4];
    int iy0 = 2 * gr - 1, ix0 = 2 * hc - 1;
#pragma unroll
    for (int rr = 0; rr < 4; ++rr) {
      int iy = iy0 + rr;
      bool yok = (unsigned)iy < 112u;
#pragma unroll
      for (int q = 0; q < 4; ++q) {
        int ix = ix0 + q;
        win[rr][q] = (yok && (unsigned)ix < 112u) ? xb[iy * 112 + ix] : 0.f;
      }
    }
#pragma unroll
    for (int c = 0; c < 8; ++c) {
      float w0_ = w1[c * 9 + 0], w1_ = w1[c * 9 + 1], w2_ = w1[c * 9 + 2],
            w3_ = w1[c * 9 + 3], w4_ = w1[c * 9 + 4], w5_ = w1[c * 9 + 5],
            w6_ = w1[c * 9 + 6], w7_ = w1[c * 9 + 7], w8_ = w1[c * 9 + 8];
      float s00 = C9(0, 0), s01 = C9(0, 1), s10 = C9(1, 0), s11 = C9(1, 1);
      float m = fmaxf(fmaxf(s00, s01), fmaxf(s10, s11));
      hs[(c * 10 + r) * HSTR + 1 + hc] = fmaxf(m + b1[c], 0.f);  // relu(max+b)
    }
  }
  __syncthreads();

  // ---- Phase 2: conv2+bias+relu+pool, thread = (f-pixel, oc-half) ----
  // oh = tid>>7: wave-pair uniform -> w2 reads stay scalar. pix lanes advance
  // by f-col -> LDS reads stride 2 floats = free 2-way conflict.
  {
    int oh = tid >> 7;      // 0|1
    int pix = tid & 127;    // 0..111 active
    if (pix < 112) {
      int y_l = pix / 28, xq = pix % 28;  // f-row-in-tile, f-col
      int r0 = 2 * y_l, c0 = 2 * xq;      // window top/left in tile coords
      float a[8][4];
#pragma unroll
      for (int o = 0; o < 8; ++o)
#pragma unroll
        for (int q = 0; q < 4; ++q) a[o][q] = 0.f;
#pragma unroll 1
      for (int ic = 0; ic < 8; ++ic) {
        float win[4][4];
        const float* hb_ = hs + (ic * 10 + r0) * HSTR + c0;
#pragma unroll
        for (int jj = 0; jj < 4; ++jj) {
          float2 u = *(const float2*)(hb_ + jj * HSTR);
          float2 v = *(const float2*)(hb_ + jj * HSTR + 2);
          win[jj][0] = u.x; win[jj][1] = u.y; win[jj][2] = v.x; win[jj][3] = v.y;
        }
#pragma unroll
        for (int o = 0; o < 8; ++o) {
          const float* wt = w2 + ((oh * 8 + o) * 8 + ic) * 9;  // wave-uniform
          float w0_ = wt[0], w1_ = wt[1], w2_ = wt[2], w3_ = wt[3],
                w4_ = wt[4], w5_ = wt[5], w6_ = wt[6], w7_ = wt[7], w8_ = wt[8];
          a[o][0] += C9(0, 0);
          a[o][1] += C9(0, 1);
          a[o][2] += C9(1, 0);
          a[o][3] += C9(1, 1);
        }
      }
      int dy = y_l & 1, dx = xq & 1;
      int p_l = (y_l >> 1) * 14 + (xq >> 1);
      float partial[4] = {0.f, 0.f, 0.f, 0.f};
#pragma unroll
      for (int o = 0; o < 8; ++o) {
        int oc = oh * 8 + o;
        float m = fmaxf(fmaxf(a[o][0], a[o][1]), fmaxf(a[o][2], a[o][3]));
        float fv = fmaxf(m + b2[oc], 0.f);  // f[oc][fy][fx]
#pragma unroll
        for (int ot = 0; ot < 4; ++ot)
          partial[ot] += fv * wp[ot * 64 + oc * 4 + dy * 2 + dx];
      }
      int slot = (dy * 2 + dx) * 2 + oh;
      *(float4*)&pfh[p_l * 32 + slot * 4] =
          make_float4(partial[0], partial[1], partial[2], partial[3]);
    }
  }
  __syncthreads();

  // ---- Phase 3: combine 8 slots + patch bias -> pfl (tile's pf slice) ----
  if (tid < 112) {
    int p = tid >> 2, ot = tid & 3;
    float sum = bp[ot];
#pragma unroll
    for (int k = 0; k < 8; ++k) sum += pfh[p * 32 + k * 4 + ot];
    pfl[tid] = sum;
  }
  __syncthreads();

  // ---- Phase 4: fc1 partial over this tile's 112 features ----
  // Global pf index of pfl[t] = 112*s + t (contiguous slice).
  {
    int j = tid >> 2, q = tid & 3;
    const float4* wrow = (const float4*)(w_fc1 + j * 784 + 112 * s + q * 28);
    const float4* pv = (const float4*)(pfl + q * 28);
    float acc = 0.f;
#pragma unroll
    for (int m = 0; m < 7; ++m) {
      float4 wv = wrow[m], fv = pv[m];
      acc += wv.x * fv.x + wv.y * fv.y + wv.z * fv.z + wv.w * fv.w;
    }
    acc += __shfl_down(acc, 2, 4);
    acc += __shfl_down(acc, 1, 4);
    if (q == 0) h1p[((long)b * 7 + s) * 64 + j] = acc;
  }
}

// ---------------- Kernel 2: combine fc1 partials + fc2 + log_softmax -------
__global__ __launch_bounds__(64) void k_tail(const float* __restrict__ h1p,
                                             const float* __restrict__ b_fc1,
                                             const float* __restrict__ w_fc2,
                                             const float* __restrict__ b_fc2,
                                             float* __restrict__ out) {
  __shared__ float h1s[64];
  __shared__ float red[11];  // [0..9] logits, [10] lse
  int b = blockIdx.x, j = threadIdx.x;
  float s = b_fc1[j];
#pragma unroll
  for (int t = 0; t < 7; ++t) s += h1p[((long)b * 7 + t) * 64 + j];
  h1s[j] = fmaxf(s, 0.f);
  __syncthreads();
  if (j < 10) {
    float acc = b_fc2[j];
    const float* wo = w_fc2 + j * 64;
#pragma unroll
    for (int k = 0; k < 64; ++k) acc += h1s[k] * wo[k];
    red[j] = acc;
  }
  __syncthreads();
  if (j == 0) {
    float mx = red[0];
    for (int o = 1; o < 10; ++o) mx = fmaxf(mx, red[o]);
    float se = 0.f;
    for (int o = 0; o < 10; ++o) se += expf(red[o] - mx);
    red[10] = mx + logf(se);
  }
  __syncthreads();
  if (j < 10) out[b * 10 + j] = red[j] - red[10];
}

extern "C" void kernel_launch(void* const* d_in, const int* in_sizes, int n_in,
                              void* d_out, int out_size, void* d_ws, size_t ws_size,
                              hipStream_t stream) {
  const float* x = (const float*)d_in[0];
  const float* w1 = (const float*)d_in[1];
  const float* b1 = (const float*)d_in[2];
  const float* w2 = (const float*)d_in[3];
  const float* b2 = (const float*)d_in[4];
  const float* wp = (const float*)d_in[5];
  const float* bp = (const float*)d_in[6];
  const float* wf1 = (const float*)d_in[7];
  const float* bf1 = (const float*)d_in[8];
  const float* wf2 = (const float*)d_in[9];
  const float* bf2 = (const float*)d_in[10];

  float* h1p = (float*)d_ws;  // [512][7][64] fc1 partials = 0.92 MB

  k_fused<<<dim3(512 * 7), 256, 0, stream>>>(x, w1, b1, w2, b2, wp, bp, wf1, h1p);
  k_tail<<<dim3(512), 64, 0, stream>>>(h1p, bf1, wf2, bf2, (float*)d_out);
}